// Round 14
// baseline (302.488 us; speedup 1.0000x reference)
//
#include <hip/hip_runtime.h>
#include <hip/hip_bf16.h>

// Decoupled RoPE MHA on MI355X (gfx950).
// B=2 S=2048 D=2048 H=16 dh=128 nope=64 rope=64
// R14: flash grid remapped to complementary-qb adjacent pairs (j=2p long,
// j=2p+1 short) so consecutive-fill block->CU assignment gives every CU a
// balanced 34 tile-units. Per-tile body identical to R13.

typedef unsigned short u16;
typedef unsigned int u32;
typedef __bf16 bf16x8 __attribute__((ext_vector_type(8)));
typedef float f32x4 __attribute__((ext_vector_type(4)));
typedef float f32x16 __attribute__((ext_vector_type(16)));

__device__ __forceinline__ u16 f2bf(float x) {
  union { __hip_bfloat16 h; u16 u; } c;
  c.h = __float2bfloat16(x);
  return c.u;
}
__device__ __forceinline__ float bf2f(u16 u) {
  union { u32 u; float f; } c;
  c.u = ((u32)u) << 16;
  return c.f;
}
__device__ __forceinline__ u32 pack2(float a, float b) {
  return (u32)f2bf(a) | ((u32)f2bf(b) << 16);
}
__device__ __forceinline__ f32x4 mfma16(bf16x8 a, bf16x8 b, f32x4 c) {
  return __builtin_amdgcn_mfma_f32_16x16x32_bf16(a, b, c, 0, 0, 0);
}
__device__ __forceinline__ f32x16 mfma32(bf16x8 a, bf16x8 b, f32x16 c) {
  return __builtin_amdgcn_mfma_f32_32x32x16_bf16(a, b, c, 0, 0, 0);
}
__device__ __forceinline__ void gload_lds16(const void* g, void* l) {
  __builtin_amdgcn_global_load_lds((__attribute__((address_space(1))) void*)g,
                                   (__attribute__((address_space(3))) void*)l,
                                   16, 0, 0);
}

// ---------------- fused cast kernel ----------------
__global__ __launch_bounds__(256) void cast_all(const float4* __restrict__ x,
                                                const float4* __restrict__ qkv,
                                                const float* __restrict__ wk,
                                                const float4* __restrict__ wo,
                                                u16* __restrict__ x_bf,
                                                u16* __restrict__ wcomb,
                                                u16* __restrict__ wo_bf) {
  int i = blockIdx.x * blockDim.x + threadIdx.x;
  const float4* src;
  u16* dst;
  int j;
  if (i < 2097152) {
    src = x; dst = x_bf; j = i;
  } else if (i < 4194304) {
    src = qkv; dst = wcomb; j = i - 2097152;
  } else if (i < 4849664) {
    j = i - 4194304;  // over 1280x2048/4; rows >=1088 are zero pad
    int r = (j * 4) >> 11;
    u32 lo = 0, hi = 0;
    if (r < 1088) {
      float4 v = ((const float4*)wk)[j];
      lo = pack2(v.x, v.y);
      hi = pack2(v.z, v.w);
    }
    ((uint2*)(wcomb + 8388608))[j] = make_uint2(lo, hi);
    return;
  } else {
    src = wo; dst = wo_bf; j = i - 4849664;
  }
  float4 v = src[j];
  ((uint2*)dst)[j] = make_uint2(pack2(v.x, v.y), pack2(v.z, v.w));
}

// ------------- GEMM BMxBN, BK=64, 4 phases/K-tile, templated (BM,BN) --------
__device__ __forceinline__ void cstore(u16* C, size_t i, float v) { C[i] = f2bf(v); }
__device__ __forceinline__ void cstore(float* C, size_t i, float v) { C[i] = v; }

template <typename CT, int BM, int BN>
__global__ __launch_bounds__(512, 2) void gemm256(const u16* __restrict__ A,
                                                  const u16* __restrict__ W,
                                                  CT* __restrict__ C,
                                                  int M, int N, int K) {
  constexpr int MI = BM / 64;
  constexpr int NI = BN / 128;
  constexpr int AH = BM * 64;
  constexpr int BH = BN * 64;
  constexpr int AL = BM / 128;
  constexpr int BL = BN / 128;
  constexpr int BOFF = 4 * AH;
  __shared__ char lds[BOFF + 4 * BH];
  const int tid = threadIdx.x;
  const int wid = tid >> 6, lane = tid & 63;
  const int lr = lane & 15, lg = lane >> 4;
  const int wr = wid >> 2, wc = wid & 3;
  const int xorv = (lr & 7) << 4;
  const int nwg = gridDim.x * gridDim.y;
  const int lin = blockIdx.y * gridDim.x + blockIdx.x;
  const int swz = (lin & 7) * (nwg >> 3) + (lin >> 3);
  const int m0 = (swz / gridDim.x) * BM;
  const int n0 = (swz % gridDim.x) * BN;
  const int nkt = K >> 6;

  f32x4 acc[2 * MI][2 * NI] = {};
  bf16x8 a[MI][2], b[2 * NI][2];

  const int o0 = tid * 16, o1 = 8192 + tid * 16;
  const int r0 = o0 >> 7, c0 = ((o0 & 127) ^ ((r0 & 7) << 4)) >> 1;
  const int r1 = o1 >> 7, c1 = ((o1 & 127) ^ ((r1 & 7) << 4)) >> 1;
  const u16* gA0[2] = {A + (size_t)(m0 + r0) * K + c0,
                       A + (size_t)(m0 + BM / 2 + r0) * K + c0};
  const u16* gA1[2] = {A + (size_t)(m0 + r1) * K + c1,
                       A + (size_t)(m0 + BM / 2 + r1) * K + c1};
  const u16* gB0[2] = {W + (size_t)(n0 + r0) * K + c0,
                       W + (size_t)(n0 + BN / 2 + r0) * K + c0};
  const u16* gB1[2] = {W + (size_t)(n0 + r1) * K + c1,
                       W + (size_t)(n0 + BN / 2 + r1) * K + c1};

  auto STAGEA = [&](int t, int h) {
    char* d_ = lds + (t & 1) * (2 * AH) + h * AH + wid * 1024;
    gload_lds16(gA0[h] + (size_t)t * 64, d_);
    if constexpr (AL == 2) gload_lds16(gA1[h] + (size_t)t * 64, d_ + 8192);
  };
  auto STAGEB = [&](int t, int h) {
    char* d_ = lds + BOFF + (t & 1) * (2 * BH) + h * BH + wid * 1024;
    gload_lds16(gB0[h] + (size_t)t * 64, d_);
    if constexpr (BL == 2) gload_lds16(gB1[h] + (size_t)t * 64, d_ + 8192);
  };
  auto WAITKEEP = [&]() {
    if constexpr (AL + BL == 4) asm volatile("s_waitcnt vmcnt(4)" ::: "memory");
    else asm volatile("s_waitcnt vmcnt(3)" ::: "memory");
  };

  STAGEA(0, 0); STAGEB(0, 0); STAGEA(0, 1); STAGEB(0, 1);
  if (nkt > 1) { STAGEA(1, 0); STAGEB(1, 0); }
  WAITKEEP();
  __builtin_amdgcn_s_barrier();

  for (int t = 0; t < nkt; ++t) {
    const char* Ab = lds + (t & 1) * (2 * AH);
    const char* Bb = lds + BOFF + (t & 1) * (2 * BH);
    const int arow = wr * (BM / 4), brow = wc * (BN / 8);
    // phase 0
#pragma unroll
    for (int mi = 0; mi < MI; mi++)
#pragma unroll
      for (int ks = 0; ks < 2; ks++)
        a[mi][ks] = *(const bf16x8*)(Ab + (arow + mi * 16 + lr) * 128 + ((lg * 16 + ks * 64) ^ xorv));
#pragma unroll
    for (int ni = 0; ni < NI; ni++)
#pragma unroll
      for (int ks = 0; ks < 2; ks++)
        b[ni][ks] = *(const bf16x8*)(Bb + (brow + ni * 16 + lr) * 128 + ((lg * 16 + ks * 64) ^ xorv));
    if (t + 1 < nkt) STAGEA(t + 1, 1);
    __builtin_amdgcn_s_barrier();
    asm volatile("s_waitcnt lgkmcnt(0)" ::: "memory");
    __builtin_amdgcn_sched_barrier(0);
    __builtin_amdgcn_s_setprio(1);
#pragma unroll
    for (int mi = 0; mi < MI; mi++)
#pragma unroll
      for (int ni = 0; ni < NI; ni++)
#pragma unroll
        for (int ks = 0; ks < 2; ks++)
          acc[mi][ni] = mfma16(a[mi][ks], b[ni][ks], acc[mi][ni]);
    __builtin_amdgcn_s_setprio(0);
    __builtin_amdgcn_s_barrier();
    // phase 1
#pragma unroll
    for (int ni = 0; ni < NI; ni++)
#pragma unroll
      for (int ks = 0; ks < 2; ks++)
        b[NI + ni][ks] = *(const bf16x8*)(Bb + BH + (brow + ni * 16 + lr) * 128 + ((lg * 16 + ks * 64) ^ xorv));
    if (t + 1 < nkt) STAGEB(t + 1, 1);
    __builtin_amdgcn_s_barrier();
    asm volatile("s_waitcnt lgkmcnt(0)" ::: "memory");
    __builtin_amdgcn_sched_barrier(0);
    __builtin_amdgcn_s_setprio(1);
#pragma unroll
    for (int mi = 0; mi < MI; mi++)
#pragma unroll
      for (int ni = 0; ni < NI; ni++)
#pragma unroll
        for (int ks = 0; ks < 2; ks++)
          acc[mi][NI + ni] = mfma16(a[mi][ks], b[NI + ni][ks], acc[mi][NI + ni]);
    __builtin_amdgcn_s_setprio(0);
    __builtin_amdgcn_s_barrier();
    // phase 2
#pragma unroll
    for (int mi = 0; mi < MI; mi++)
#pragma unroll
      for (int ks = 0; ks < 2; ks++)
        a[mi][ks] = *(const bf16x8*)(Ab + AH + (arow + mi * 16 + lr) * 128 + ((lg * 16 + ks * 64) ^ xorv));
    if (t + 2 < nkt) STAGEA(t + 2, 0);
    __builtin_amdgcn_s_barrier();
    asm volatile("s_waitcnt lgkmcnt(0)" ::: "memory");
    __builtin_amdgcn_sched_barrier(0);
    __builtin_amdgcn_s_setprio(1);
#pragma unroll
    for (int mi = 0; mi < MI; mi++)
#pragma unroll
      for (int ni = 0; ni < NI; ni++)
#pragma unroll
        for (int ks = 0; ks < 2; ks++)
          acc[MI + mi][ni] = mfma16(a[mi][ks], b[ni][ks], acc[MI + mi][ni]);
    __builtin_amdgcn_s_setprio(0);
    __builtin_amdgcn_s_barrier();
    // phase 3
    if (t + 2 < nkt) {
      STAGEB(t + 2, 0);
      WAITKEEP();
    } else if (t + 1 < nkt) {
      asm volatile("s_waitcnt vmcnt(0)" ::: "memory");
    }
    __builtin_amdgcn_s_barrier();
    asm volatile("s_waitcnt lgkmcnt(0)" ::: "memory");
    __builtin_amdgcn_sched_barrier(0);
    __builtin_amdgcn_s_setprio(1);
#pragma unroll
    for (int mi = 0; mi < MI; mi++)
#pragma unroll
      for (int ni = 0; ni < NI; ni++)
#pragma unroll
        for (int ks = 0; ks < 2; ks++)
          acc[MI + mi][NI + ni] = mfma16(a[mi][ks], b[NI + ni][ks], acc[MI + mi][NI + ni]);
    __builtin_amdgcn_s_setprio(0);
    __builtin_amdgcn_s_barrier();
  }

#pragma unroll
  for (int Mh = 0; Mh < 2; Mh++)
#pragma unroll
    for (int mi = 0; mi < MI; mi++) {
      int row = m0 + Mh * (BM / 2) + wr * (BM / 4) + mi * 16 + lg * 4;
#pragma unroll
      for (int Nh = 0; Nh < 2; Nh++)
#pragma unroll
        for (int ni = 0; ni < NI; ni++) {
          int col = n0 + Nh * (BN / 2) + wc * (BN / 8) + ni * 16 + lr;
#pragma unroll
          for (int r = 0; r < 4; r++)
            cstore(C, (size_t)(row + r) * N + col, acc[Mh * MI + mi][Nh * NI + ni][r]);
        }
    }
}

// ---------------- RoPE: Q in-place in QVK + K scatter ----------------
__global__ __launch_bounds__(256) void rope_scatter2(u16* __restrict__ QVK,
                                                     u16* __restrict__ kh,
                                                     float* __restrict__ k_out, int S) {
  const int row = blockIdx.x;  // b*S + s
  const int b = row >> 11, s = row & 2047;
  const int tid = threadIdx.x;
  __shared__ float kr[64];
  const float LOG1E4_64 = 0.14391156511f;  // ln(10000)/64
  u16* qrow = QVK + (size_t)row * 5376;
  if (tid < 32) {
    float freq = __expf(-(float)tid * LOG1E4_64);
    float sn, c;
    __sincosf((float)s * freq, &sn, &c);
    float a = bf2f(qrow[5120 + tid]);
    float bb = bf2f(qrow[5152 + tid]);
    kr[tid] = a * c - bb * sn;
    kr[tid + 32] = bb * c + a * sn;
  }
  for (int idx = tid; idx < 512; idx += 256) {
    int h = idx >> 5, jj = idx & 31;
    float freq = __expf(-(float)jj * LOG1E4_64);
    float sn, c;
    __sincosf((float)s * freq, &sn, &c);
    u16* p1 = qrow + h * 128 + 64 + jj;
    u16* p2 = qrow + h * 128 + 96 + jj;
    float x1 = bf2f(*p1), x2 = bf2f(*p2);
    *p1 = f2bf(x1 * c - x2 * sn);
    *p2 = f2bf(x2 * c + x1 * sn);
  }
  __syncthreads();
  for (int idx = tid; idx < 2048; idx += 256) {
    int h = idx >> 7, d = idx & 127;
    float val = (d < 64) ? bf2f(qrow[4096 + h * 64 + d]) : kr[d - 64];
    size_t o = ((size_t)(b * 16 + h) * S + s) * 128 + d;
    kh[o] = f2bf(val);
    k_out[o] = val;
  }
}

// ---------------- V: write v_heads fp32 + transposed Vt (B,H,128,S) ----------
__global__ __launch_bounds__(256) void v_scatter(const u16* __restrict__ QVK,
                                                 u16* __restrict__ vt,
                                                 float* __restrict__ v_out, int S) {
  const int blk = blockIdx.x;
  const int st = blk & 63;
  const int dt = (blk >> 6) & 3;
  const int bh = blk >> 8;
  const int b = bh >> 4, h = bh & 15;
  __shared__ u16 t[32][34];
  const int tx = threadIdx.x & 31, ty = threadIdx.x >> 5;
  const int s0 = st * 32, d0 = dt * 32;
#pragma unroll
  for (int i = 0; i < 4; i++) {
    int sl = ty + 8 * i;
    u16 u = QVK[(size_t)(b * S + s0 + sl) * 5376 + 2048 + h * 128 + d0 + tx];
    t[sl][tx] = u;
    v_out[((size_t)bh * S + s0 + sl) * 128 + d0 + tx] = bf2f(u);
  }
  __syncthreads();
#pragma unroll
  for (int i = 0; i < 4; i++) {
    int dl = ty + 8 * i;
    vt[((size_t)bh * 128 + d0 + dl) * S + s0 + tx] = t[tx][dl];
  }
}

// --------- flash attention v11: R13 body + complementary-qb pairing ---------
// Grid 512 = 256 adjacent pairs: j=2p -> qb=15-(p>>5) (long), j=2p+1 ->
// qb=(p>>5) (short), bh=p&31. Under block-major consecutive fill, each CU
// hosts one long + one short block = 34 tile-units (balanced).
__global__ __launch_bounds__(256) void flash_attn11(const u16* __restrict__ QVK,
                                                    const u16* __restrict__ Kh,
                                                    const u16* __restrict__ Vt,
                                                    u16* __restrict__ attn, int S) {
  __shared__ char lds[66048];
  const int tid = threadIdx.x, wid = tid >> 6, lane = tid & 63;
  const int jj = blockIdx.x;
  const int p = jj >> 1, kq = p >> 5;
  const int bh = p & 31;
  const int qb = (jj & 1) ? kq : 15 - kq;
  const int q0w = qb * 128 + wid * 32;
  const int b = bh >> 4, h = bh & 15;
  const int r32 = lane & 31, hh = lane >> 5;
  const u16* Qb = QVK + (size_t)b * S * 5376 + h * 128;
  const u16* Kb = Kh + (size_t)bh * S * 128;
  const u16* Vb = Vt + (size_t)bh * 128 * S;
  const int qg = q0w + r32;
  const int xr = (r32 & 7) << 4;
  char* const Pc = lds + 65536 + wid * 128;

  // stage sources (pre-swizzled), 4 loads per tile for K and for V
  const u16 *srcK[4], *srcV[4];
#pragma unroll
  for (int i = 0; i < 4; i++) {
    int o = i * 4096 + tid * 16;
    int rK = o >> 8, cbK = (o & 255) ^ ((rK & 7) << 4);
    srcK[i] = Kb + rK * 128 + (cbK >> 1);
    int dV = o >> 7, kbV = (o & 127) ^ ((dV & 7) << 4);
    srcV[i] = Vb + (size_t)dV * S + (kbV >> 1);
  }

  bf16x8 qf[8];
#pragma unroll
  for (int f = 0; f < 8; f++)
    qf[f] = *(const bf16x8*)(Qb + (size_t)qg * 5376 + f * 16 + hh * 8);

  f32x16 acc[4] = {};
  float m = -INFINITY, l = 0.f;
  const float sc = 0.08838834764831845f;  // 1/sqrt(128)
  const int ktiles = 2 * qb + 2;

  // prologue: stage tile 0 into K0/V0
#pragma unroll
  for (int i = 0; i < 4; i++) {
    gload_lds16(srcK[i], lds + i * 4096 + wid * 1024);
    gload_lds16(srcV[i], lds + 32768 + i * 4096 + wid * 1024);
  }
  asm volatile("s_waitcnt vmcnt(0)" ::: "memory");
  __builtin_amdgcn_s_barrier();

  for (int kt = 0; kt < ktiles; ++kt) {
    const bool more = (kt + 1 < ktiles);
    if (more) {
      const int dst = ((kt + 1) & 1) << 14;
#pragma unroll
      for (int i = 0; i < 4; i++) {
        gload_lds16(srcK[i] + (size_t)(kt + 1) * 8192,
                    lds + dst + i * 4096 + wid * 1024);
        gload_lds16(srcV[i] + (size_t)(kt + 1) * 64,
                    lds + 32768 + dst + i * 4096 + wid * 1024);
      }
      asm volatile("s_waitcnt vmcnt(8)" ::: "memory");  // drain stage(kt)
    } else {
      asm volatile("s_waitcnt vmcnt(0)" ::: "memory");
    }
    __builtin_amdgcn_s_barrier();

    const char* Kt = lds + (kt & 1) * 16384;
    const char* Vl = lds + 32768 + (kt & 1) * 16384;
    const int kbg = kt * 64;
    const bool active = (kbg <= q0w + 31);  // wave-uniform
    if (active) {
      u32 u[16];
      f32x16 s[2] = {};
      __builtin_amdgcn_s_setprio(1);
#pragma unroll
      for (int kg = 0; kg < 2; kg++) {
        const char* Kq = Kt + (kg * 32 + r32) * 256;
#pragma unroll
        for (int f = 0; f < 8; f++) {
          bf16x8 kf = *(const bf16x8*)(Kq + ((f * 32 + hh * 16) ^ xr));
          s[kg] = mfma32(kf, qf[f], s[kg]);
        }
      }
      __builtin_amdgcn_s_setprio(0);
      const bool maskt = (kbg + 63 > q0w);
      if (maskt) {
#pragma unroll
        for (int kg = 0; kg < 2; kg++)
#pragma unroll
          for (int r = 0; r < 16; r++)
            if (kbg + kg * 32 + (r & 3) + 8 * (r >> 2) + 4 * hh > qg)
              s[kg][r] = -1e30f;
      }
      // tree max over 32 values
      float mx[16];
#pragma unroll
      for (int r = 0; r < 16; r++) mx[r] = fmaxf(s[0][r], s[1][r]);
#pragma unroll
      for (int st = 8; st > 0; st >>= 1)
#pragma unroll
        for (int r = 0; r < 8; r++)
          if (r < st) mx[r] = fmaxf(mx[r], mx[r + st]);
      float tm = mx[0];
      tm = fmaxf(tm, __shfl_xor(tm, 32));
      // defer-max: rescale only when raw max grew by > 64 (5.7 nats scaled)
      if (!__all(tm <= m + 64.0f)) {
        float mnew = fmaxf(m, tm);
        float corr = __expf((m - mnew) * sc);
        m = mnew;
        l *= corr;
        if (lane < 32) *(float*)(Pc + r32 * 4) = corr;
        asm volatile("s_waitcnt lgkmcnt(0)" ::: "memory");
        __builtin_amdgcn_sched_barrier(0);
        f32x4 c0 = *(const f32x4*)(Pc + (4 * hh) * 4);
        f32x4 c1 = *(const f32x4*)(Pc + (8 + 4 * hh) * 4);
        f32x4 c2 = *(const f32x4*)(Pc + (16 + 4 * hh) * 4);
        f32x4 c3 = *(const f32x4*)(Pc + (24 + 4 * hh) * 4);
#pragma unroll
        for (int dg = 0; dg < 4; dg++)
#pragma unroll
          for (int r = 0; r < 16; r++) {
            float cr = (r >> 2) == 0 ? c0[r & 3]
                     : (r >> 2) == 1 ? c1[r & 3]
                     : (r >> 2) == 2 ? c2[r & 3] : c3[r & 3];
            acc[dg][r] *= cr;
          }
      }
      const float nms = -m * sc;
      float sm[16];
#pragma unroll
      for (int kg = 0; kg < 2; kg++)
#pragma unroll
        for (int r = 0; r < 16; r++)
          s[kg][r] = __expf(fmaf(s[kg][r], sc, nms));
      // tree sum over 32 values
#pragma unroll
      for (int r = 0; r < 16; r++) sm[r] = s[0][r] + s[1][r];
#pragma unroll
      for (int st = 8; st > 0; st >>= 1)
#pragma unroll
        for (int r = 0; r < 8; r++)
          if (r < st) sm[r] = sm[r] + sm[r + st];
      float ts = sm[0];
      ts += __shfl_xor(ts, 32);
      l += ts;
      // pack P pairs (keys kg*32 + 8*(i>>1) + 4*hh + 2*(i&1) + {0,1})
#pragma unroll
      for (int kg = 0; kg < 2; kg++)
#pragma unroll
        for (int i = 0; i < 8; i++)
          u[kg * 8 + i] = pack2(s[kg][2 * i], s[kg][2 * i + 1]);

      // PV: V(kt) ready (waited at top)
      __builtin_amdgcn_s_setprio(1);
#pragma unroll
      for (int dg = 0; dg < 4; dg++) {
        const char* Vq = Vl + (dg * 32 + r32) * 128;
#pragma unroll
        for (int ss = 0; ss < 4; ss++) {
          // B-frag keys match A-frag slot keys: 16ss+4hh+{0..3}, 16ss+8+4hh+{0..3}
          uint2 vlo = *(const uint2*)(Vq + ((ss * 32 + 8 * hh) ^ xr));
          uint2 vhi = *(const uint2*)(Vq + ((ss * 32 + 16 + 8 * hh) ^ xr));
          union { u32 w[4]; bf16x8 v; } vb, pa;
          vb.w[0] = vlo.x; vb.w[1] = vlo.y; vb.w[2] = vhi.x; vb.w[3] = vhi.y;
          pa.w[0] = u[ss * 4 + 0];
          pa.w[1] = u[ss * 4 + 1];
          pa.w[2] = u[ss * 4 + 2];
          pa.w[3] = u[ss * 4 + 3];
          acc[dg] = mfma32(pa.v, vb.v, acc[dg]);
        }
      }
      __builtin_amdgcn_s_setprio(0);
    }
    __builtin_amdgcn_s_barrier();  // reads of bufs(kt) done; safe to overwrite
  }

  float linv = 1.0f / l;
  if (lane < 32) *(float*)(Pc + r32 * 4) = linv;
  asm volatile("s_waitcnt lgkmcnt(0)" ::: "memory");
  __builtin_amdgcn_sched_barrier(0);
  f32x4 l0 = *(const f32x4*)(Pc + (4 * hh) * 4);
  f32x4 l1 = *(const f32x4*)(Pc + (8 + 4 * hh) * 4);
  f32x4 l2 = *(const f32x4*)(Pc + (16 + 4 * hh) * 4);
  f32x4 l3 = *(const f32x4*)(Pc + (24 + 4 * hh) * 4);
  u16* ab = attn + (size_t)(b * S + q0w) * 2048 + h * 128;
#pragma unroll
  for (int dg = 0; dg < 4; dg++)
#pragma unroll
    for (int r = 0; r < 16; r++) {
      int rowl = (r & 3) + 8 * (r >> 2) + 4 * hh;
      float li = (r >> 2) == 0 ? l0[r & 3]
               : (r >> 2) == 1 ? l1[r & 3]
               : (r >> 2) == 2 ? l2[r & 3] : l3[r & 3];
      ab[(size_t)rowl * 2048 + dg * 32 + r32] = f2bf(acc[dg][r] * li);
    }
}

// ---------------- launch ----------------
extern "C" void kernel_launch(void* const* d_in, const int* in_sizes, int n_in,
                              void* d_out, int out_size, void* d_ws, size_t ws_size,
                              hipStream_t stream) {
  (void)in_sizes; (void)n_in; (void)out_size; (void)ws_size;
  const int S = 2048;
  const float* x = (const float*)d_in[0];
  const float* qkv = (const float*)d_in[1];
  const float* wk = (const float*)d_in[2];
  const float* wo = (const float*)d_in[3];
  float* out = (float*)d_out;
  float* k_out = out + (size_t)8388608;
  float* v_out = out + (size_t)16777216;

  char* ws = (char*)d_ws;
  u16* x_bf  = (u16*)(ws + 0);          // 16.78 MB (later: attn_bf)
  u16* wcomb = (u16*)(ws + 16777216);   // 22.02 MB (5376x2048) (later: k_bf)
  u16* wo_bf = (u16*)(ws + 38797312);   // 8.39 MB
  u16* qvk   = (u16*)(ws + 47185920);   // 44.04 MB (4096x5376)
  u16* vt_bf = (u16*)(ws + 91226112);   // 16.78 MB (B,H,128,S)
  u16* attn_bf = x_bf;
  u16* k_bf = wcomb;

  cast_all<<<23040, 256, 0, stream>>>((const float4*)x, (const float4*)qkv, wk,
                                      (const float4*)wo, x_bf, wcomb, wo_bf);

  gemm256<u16, 256, 256><<<dim3(16, 16), 512, 0, stream>>>(x_bf, wcomb, qvk,
                                                           4096, 5376, 2048);
  gemm256<u16, 256, 128><<<dim3(10, 16), 512, 0, stream>>>(
      x_bf, wcomb + (size_t)4096 * 2048, qvk + 4096, 4096, 5376, 2048);
  rope_scatter2<<<4096, 256, 0, stream>>>(qvk, k_bf, k_out, S);
  v_scatter<<<8192, 256, 0, stream>>>(qvk, vt_bf, v_out, S);
  flash_attn11<<<512, 256, 0, stream>>>(qvk, k_bf, vt_bf, attn_bf, S);
  gemm256<float, 128, 256><<<dim3(8, 32), 512, 0, stream>>>(attn_bf, wo_bf, out,
                                                            4096, 2048, 2048);
}

// Round 15
// 258.744 us; speedup vs baseline: 1.1691x; 1.1691x over previous
//
#include <hip/hip_runtime.h>
#include <hip/hip_bf16.h>

// Decoupled RoPE MHA on MI355X (gfx950).
// B=2 S=2048 D=2048 H=16 dh=128 nope=64 rope=64
// R15: revert flash to R13 (best verified). Merge v_scatter into the K-GEMM
// dispatch: blocks 0..159 = 256x128 K-GEMM, blocks 160..4255 = v_scatter
// (2 units each, 512 thr) -> scatter hides under the GEMM round's idle CUs.

typedef unsigned short u16;
typedef unsigned int u32;
typedef __bf16 bf16x8 __attribute__((ext_vector_type(8)));
typedef float f32x4 __attribute__((ext_vector_type(4)));
typedef float f32x16 __attribute__((ext_vector_type(16)));

__device__ __forceinline__ u16 f2bf(float x) {
  union { __hip_bfloat16 h; u16 u; } c;
  c.h = __float2bfloat16(x);
  return c.u;
}
__device__ __forceinline__ float bf2f(u16 u) {
  union { u32 u; float f; } c;
  c.u = ((u32)u) << 16;
  return c.f;
}
__device__ __forceinline__ u32 pack2(float a, float b) {
  return (u32)f2bf(a) | ((u32)f2bf(b) << 16);
}
__device__ __forceinline__ f32x4 mfma16(bf16x8 a, bf16x8 b, f32x4 c) {
  return __builtin_amdgcn_mfma_f32_16x16x32_bf16(a, b, c, 0, 0, 0);
}
__device__ __forceinline__ f32x16 mfma32(bf16x8 a, bf16x8 b, f32x16 c) {
  return __builtin_amdgcn_mfma_f32_32x32x16_bf16(a, b, c, 0, 0, 0);
}
__device__ __forceinline__ void gload_lds16(const void* g, void* l) {
  __builtin_amdgcn_global_load_lds((__attribute__((address_space(1))) void*)g,
                                   (__attribute__((address_space(3))) void*)l,
                                   16, 0, 0);
}

// ---------------- fused cast kernel ----------------
__global__ __launch_bounds__(256) void cast_all(const float4* __restrict__ x,
                                                const float4* __restrict__ qkv,
                                                const float* __restrict__ wk,
                                                const float4* __restrict__ wo,
                                                u16* __restrict__ x_bf,
                                                u16* __restrict__ wcomb,
                                                u16* __restrict__ wo_bf) {
  int i = blockIdx.x * blockDim.x + threadIdx.x;
  const float4* src;
  u16* dst;
  int j;
  if (i < 2097152) {
    src = x; dst = x_bf; j = i;
  } else if (i < 4194304) {
    src = qkv; dst = wcomb; j = i - 2097152;
  } else if (i < 4849664) {
    j = i - 4194304;  // over 1280x2048/4; rows >=1088 are zero pad
    int r = (j * 4) >> 11;
    u32 lo = 0, hi = 0;
    if (r < 1088) {
      float4 v = ((const float4*)wk)[j];
      lo = pack2(v.x, v.y);
      hi = pack2(v.z, v.w);
    }
    ((uint2*)(wcomb + 8388608))[j] = make_uint2(lo, hi);
    return;
  } else {
    src = wo; dst = wo_bf; j = i - 4849664;
  }
  float4 v = src[j];
  ((uint2*)dst)[j] = make_uint2(pack2(v.x, v.y), pack2(v.z, v.w));
}

// ------------- GEMM core: BMxBN tile at (m0,n0), BK=64, 4 phases/K-tile -----
__device__ __forceinline__ void cstore(u16* C, size_t i, float v) { C[i] = f2bf(v); }
__device__ __forceinline__ void cstore(float* C, size_t i, float v) { C[i] = v; }

template <typename CT, int BM, int BN>
__device__ __forceinline__ void gemm_core(const u16* __restrict__ A,
                                          const u16* __restrict__ W,
                                          CT* __restrict__ C,
                                          int M, int N, int K,
                                          int m0, int n0, char* lds) {
  constexpr int MI = BM / 64;
  constexpr int NI = BN / 128;
  constexpr int AH = BM * 64;
  constexpr int BH = BN * 64;
  constexpr int AL = BM / 128;
  constexpr int BL = BN / 128;
  constexpr int BOFF = 4 * AH;
  const int tid = threadIdx.x;
  const int wid = tid >> 6, lane = tid & 63;
  const int lr = lane & 15, lg = lane >> 4;
  const int wr = wid >> 2, wc = wid & 3;
  const int xorv = (lr & 7) << 4;
  const int nkt = K >> 6;

  f32x4 acc[2 * MI][2 * NI] = {};
  bf16x8 a[MI][2], b[2 * NI][2];

  const int o0 = tid * 16, o1 = 8192 + tid * 16;
  const int r0 = o0 >> 7, c0 = ((o0 & 127) ^ ((r0 & 7) << 4)) >> 1;
  const int r1 = o1 >> 7, c1 = ((o1 & 127) ^ ((r1 & 7) << 4)) >> 1;
  const u16* gA0[2] = {A + (size_t)(m0 + r0) * K + c0,
                       A + (size_t)(m0 + BM / 2 + r0) * K + c0};
  const u16* gA1[2] = {A + (size_t)(m0 + r1) * K + c1,
                       A + (size_t)(m0 + BM / 2 + r1) * K + c1};
  const u16* gB0[2] = {W + (size_t)(n0 + r0) * K + c0,
                       W + (size_t)(n0 + BN / 2 + r0) * K + c0};
  const u16* gB1[2] = {W + (size_t)(n0 + r1) * K + c1,
                       W + (size_t)(n0 + BN / 2 + r1) * K + c1};

  auto STAGEA = [&](int t, int h) {
    char* d_ = lds + (t & 1) * (2 * AH) + h * AH + wid * 1024;
    gload_lds16(gA0[h] + (size_t)t * 64, d_);
    if constexpr (AL == 2) gload_lds16(gA1[h] + (size_t)t * 64, d_ + 8192);
  };
  auto STAGEB = [&](int t, int h) {
    char* d_ = lds + BOFF + (t & 1) * (2 * BH) + h * BH + wid * 1024;
    gload_lds16(gB0[h] + (size_t)t * 64, d_);
    if constexpr (BL == 2) gload_lds16(gB1[h] + (size_t)t * 64, d_ + 8192);
  };
  auto WAITKEEP = [&]() {
    if constexpr (AL + BL == 4) asm volatile("s_waitcnt vmcnt(4)" ::: "memory");
    else asm volatile("s_waitcnt vmcnt(3)" ::: "memory");
  };

  STAGEA(0, 0); STAGEB(0, 0); STAGEA(0, 1); STAGEB(0, 1);
  if (nkt > 1) { STAGEA(1, 0); STAGEB(1, 0); }
  WAITKEEP();
  __builtin_amdgcn_s_barrier();

  for (int t = 0; t < nkt; ++t) {
    const char* Ab = lds + (t & 1) * (2 * AH);
    const char* Bb = lds + BOFF + (t & 1) * (2 * BH);
    const int arow = wr * (BM / 4), brow = wc * (BN / 8);
    // phase 0
#pragma unroll
    for (int mi = 0; mi < MI; mi++)
#pragma unroll
      for (int ks = 0; ks < 2; ks++)
        a[mi][ks] = *(const bf16x8*)(Ab + (arow + mi * 16 + lr) * 128 + ((lg * 16 + ks * 64) ^ xorv));
#pragma unroll
    for (int ni = 0; ni < NI; ni++)
#pragma unroll
      for (int ks = 0; ks < 2; ks++)
        b[ni][ks] = *(const bf16x8*)(Bb + (brow + ni * 16 + lr) * 128 + ((lg * 16 + ks * 64) ^ xorv));
    if (t + 1 < nkt) STAGEA(t + 1, 1);
    __builtin_amdgcn_s_barrier();
    asm volatile("s_waitcnt lgkmcnt(0)" ::: "memory");
    __builtin_amdgcn_sched_barrier(0);
    __builtin_amdgcn_s_setprio(1);
#pragma unroll
    for (int mi = 0; mi < MI; mi++)
#pragma unroll
      for (int ni = 0; ni < NI; ni++)
#pragma unroll
        for (int ks = 0; ks < 2; ks++)
          acc[mi][ni] = mfma16(a[mi][ks], b[ni][ks], acc[mi][ni]);
    __builtin_amdgcn_s_setprio(0);
    __builtin_amdgcn_s_barrier();
    // phase 1
#pragma unroll
    for (int ni = 0; ni < NI; ni++)
#pragma unroll
      for (int ks = 0; ks < 2; ks++)
        b[NI + ni][ks] = *(const bf16x8*)(Bb + BH + (brow + ni * 16 + lr) * 128 + ((lg * 16 + ks * 64) ^ xorv));
    if (t + 1 < nkt) STAGEB(t + 1, 1);
    __builtin_amdgcn_s_barrier();
    asm volatile("s_waitcnt lgkmcnt(0)" ::: "memory");
    __builtin_amdgcn_sched_barrier(0);
    __builtin_amdgcn_s_setprio(1);
#pragma unroll
    for (int mi = 0; mi < MI; mi++)
#pragma unroll
      for (int ni = 0; ni < NI; ni++)
#pragma unroll
        for (int ks = 0; ks < 2; ks++)
          acc[mi][NI + ni] = mfma16(a[mi][ks], b[NI + ni][ks], acc[mi][NI + ni]);
    __builtin_amdgcn_s_setprio(0);
    __builtin_amdgcn_s_barrier();
    // phase 2
#pragma unroll
    for (int mi = 0; mi < MI; mi++)
#pragma unroll
      for (int ks = 0; ks < 2; ks++)
        a[mi][ks] = *(const bf16x8*)(Ab + AH + (arow + mi * 16 + lr) * 128 + ((lg * 16 + ks * 64) ^ xorv));
    if (t + 2 < nkt) STAGEA(t + 2, 0);
    __builtin_amdgcn_s_barrier();
    asm volatile("s_waitcnt lgkmcnt(0)" ::: "memory");
    __builtin_amdgcn_sched_barrier(0);
    __builtin_amdgcn_s_setprio(1);
#pragma unroll
    for (int mi = 0; mi < MI; mi++)
#pragma unroll
      for (int ni = 0; ni < NI; ni++)
#pragma unroll
        for (int ks = 0; ks < 2; ks++)
          acc[MI + mi][ni] = mfma16(a[mi][ks], b[ni][ks], acc[MI + mi][ni]);
    __builtin_amdgcn_s_setprio(0);
    __builtin_amdgcn_s_barrier();
    // phase 3
    if (t + 2 < nkt) {
      STAGEB(t + 2, 0);
      WAITKEEP();
    } else if (t + 1 < nkt) {
      asm volatile("s_waitcnt vmcnt(0)" ::: "memory");
    }
    __builtin_amdgcn_s_barrier();
    asm volatile("s_waitcnt lgkmcnt(0)" ::: "memory");
    __builtin_amdgcn_sched_barrier(0);
    __builtin_amdgcn_s_setprio(1);
#pragma unroll
    for (int mi = 0; mi < MI; mi++)
#pragma unroll
      for (int ni = 0; ni < NI; ni++)
#pragma unroll
        for (int ks = 0; ks < 2; ks++)
          acc[MI + mi][NI + ni] = mfma16(a[mi][ks], b[NI + ni][ks], acc[MI + mi][NI + ni]);
    __builtin_amdgcn_s_setprio(0);
    __builtin_amdgcn_s_barrier();
  }

#pragma unroll
  for (int Mh = 0; Mh < 2; Mh++)
#pragma unroll
    for (int mi = 0; mi < MI; mi++) {
      int row = m0 + Mh * (BM / 2) + wr * (BM / 4) + mi * 16 + lg * 4;
#pragma unroll
      for (int Nh = 0; Nh < 2; Nh++)
#pragma unroll
        for (int ni = 0; ni < NI; ni++) {
          int col = n0 + Nh * (BN / 2) + wc * (BN / 8) + ni * 16 + lr;
#pragma unroll
          for (int r = 0; r < 4; r++)
            cstore(C, (size_t)(row + r) * N + col, acc[Mh * MI + mi][Nh * NI + ni][r]);
        }
    }
}

template <typename CT, int BM, int BN>
__global__ __launch_bounds__(512, 2) void gemm256(const u16* __restrict__ A,
                                                  const u16* __restrict__ W,
                                                  CT* __restrict__ C,
                                                  int M, int N, int K) {
  __shared__ char lds[4 * BM * 64 + 4 * BN * 64];
  const int nwg = gridDim.x * gridDim.y;
  const int lin = blockIdx.y * gridDim.x + blockIdx.x;
  const int swz = (lin & 7) * (nwg >> 3) + (lin >> 3);
  const int m0 = (swz / gridDim.x) * BM;
  const int n0 = (swz % gridDim.x) * BN;
  gemm_core<CT, BM, BN>(A, W, C, M, N, K, m0, n0, lds);
}

// ------- merged: K-GEMM (blocks 0..159, 256x128) + v_scatter (rest) ---------
// v_scatter: write v_heads fp32 + transposed Vt (B,H,128,S); 2 units/block.
__global__ __launch_bounds__(512, 2) void kgemm_vscatter(
    const u16* __restrict__ A, const u16* __restrict__ Wk, u16* __restrict__ Ck,
    const u16* __restrict__ QVK, u16* __restrict__ vt, float* __restrict__ v_out,
    int S) {
  __shared__ char lds[98304];
  if (blockIdx.x < 160) {
    const int lin = blockIdx.x;
    const int swz = (lin & 7) * 20 + (lin >> 3);  // bijective over 160 = 8x20
    const int m0 = (swz / 10) * 256, n0 = (swz % 10) * 128;
    gemm_core<u16, 256, 128>(A, Wk, Ck, 4096, 5376, 2048, m0, n0, lds);
    return;
  }
  // v_scatter: two 256-thread units per block
  const int uh = threadIdx.x >> 8;            // unit half 0/1
  const int t8 = threadIdx.x & 255;
  const int blk = (blockIdx.x - 160) * 2 + uh;  // 0..8191
  const int st = blk & 63;
  const int dt = (blk >> 6) & 3;
  const int bh = blk >> 8;
  const int b = bh >> 4, h = bh & 15;
  u16(*t)[34] = (u16(*)[34])(lds + uh * 2432);
  const int tx = t8 & 31, ty = t8 >> 5;
  const int s0 = st * 32, d0 = dt * 32;
#pragma unroll
  for (int i = 0; i < 4; i++) {
    int sl = ty + 8 * i;
    u16 u = QVK[(size_t)(b * S + s0 + sl) * 5376 + 2048 + h * 128 + d0 + tx];
    t[sl][tx] = u;
    v_out[((size_t)bh * S + s0 + sl) * 128 + d0 + tx] = bf2f(u);
  }
  __syncthreads();
#pragma unroll
  for (int i = 0; i < 4; i++) {
    int dl = ty + 8 * i;
    vt[((size_t)bh * 128 + d0 + dl) * S + s0 + tx] = t[tx][dl];
  }
}

// ---------------- RoPE: Q in-place in QVK + K scatter ----------------
__global__ __launch_bounds__(256) void rope_scatter2(u16* __restrict__ QVK,
                                                     u16* __restrict__ kh,
                                                     float* __restrict__ k_out, int S) {
  const int row = blockIdx.x;  // b*S + s
  const int b = row >> 11, s = row & 2047;
  const int tid = threadIdx.x;
  __shared__ float kr[64];
  const float LOG1E4_64 = 0.14391156511f;  // ln(10000)/64
  u16* qrow = QVK + (size_t)row * 5376;
  if (tid < 32) {
    float freq = __expf(-(float)tid * LOG1E4_64);
    float sn, c;
    __sincosf((float)s * freq, &sn, &c);
    float a = bf2f(qrow[5120 + tid]);
    float bb = bf2f(qrow[5152 + tid]);
    kr[tid] = a * c - bb * sn;
    kr[tid + 32] = bb * c + a * sn;
  }
  for (int idx = tid; idx < 512; idx += 256) {
    int h = idx >> 5, jj = idx & 31;
    float freq = __expf(-(float)jj * LOG1E4_64);
    float sn, c;
    __sincosf((float)s * freq, &sn, &c);
    u16* p1 = qrow + h * 128 + 64 + jj;
    u16* p2 = qrow + h * 128 + 96 + jj;
    float x1 = bf2f(*p1), x2 = bf2f(*p2);
    *p1 = f2bf(x1 * c - x2 * sn);
    *p2 = f2bf(x2 * c + x1 * sn);
  }
  __syncthreads();
  for (int idx = tid; idx < 2048; idx += 256) {
    int h = idx >> 7, d = idx & 127;
    float val = (d < 64) ? bf2f(qrow[4096 + h * 64 + d]) : kr[d - 64];
    size_t o = ((size_t)(b * 16 + h) * S + s) * 128 + d;
    kh[o] = f2bf(val);
    k_out[o] = val;
  }
}

// --------- flash attention v10 (R13): 32x32 MFMA, K+V double-buffered -------
__global__ __launch_bounds__(256) void flash_attn10(const u16* __restrict__ QVK,
                                                    const u16* __restrict__ Kh,
                                                    const u16* __restrict__ Vt,
                                                    u16* __restrict__ attn, int S) {
  __shared__ char lds[66048];
  const int tid = threadIdx.x, wid = tid >> 6, lane = tid & 63;
  const int bh = blockIdx.x & 31;
  const int qb = 15 - (int)(blockIdx.x >> 5);  // longest blocks first
  const int q0w = qb * 128 + wid * 32;
  const int b = bh >> 4, h = bh & 15;
  const int r32 = lane & 31, hh = lane >> 5;
  const u16* Qb = QVK + (size_t)b * S * 5376 + h * 128;
  const u16* Kb = Kh + (size_t)bh * S * 128;
  const u16* Vb = Vt + (size_t)bh * 128 * S;
  const int qg = q0w + r32;
  const int xr = (r32 & 7) << 4;
  char* const Pc = lds + 65536 + wid * 128;

  const u16 *srcK[4], *srcV[4];
#pragma unroll
  for (int i = 0; i < 4; i++) {
    int o = i * 4096 + tid * 16;
    int rK = o >> 8, cbK = (o & 255) ^ ((rK & 7) << 4);
    srcK[i] = Kb + rK * 128 + (cbK >> 1);
    int dV = o >> 7, kbV = (o & 127) ^ ((dV & 7) << 4);
    srcV[i] = Vb + (size_t)dV * S + (kbV >> 1);
  }

  bf16x8 qf[8];
#pragma unroll
  for (int f = 0; f < 8; f++)
    qf[f] = *(const bf16x8*)(Qb + (size_t)qg * 5376 + f * 16 + hh * 8);

  f32x16 acc[4] = {};
  float m = -INFINITY, l = 0.f;
  const float sc = 0.08838834764831845f;  // 1/sqrt(128)
  const int ktiles = 2 * qb + 2;

  // prologue: stage tile 0 into K0/V0
#pragma unroll
  for (int i = 0; i < 4; i++) {
    gload_lds16(srcK[i], lds + i * 4096 + wid * 1024);
    gload_lds16(srcV[i], lds + 32768 + i * 4096 + wid * 1024);
  }
  asm volatile("s_waitcnt vmcnt(0)" ::: "memory");
  __builtin_amdgcn_s_barrier();

  for (int kt = 0; kt < ktiles; ++kt) {
    const bool more = (kt + 1 < ktiles);
    if (more) {
      const int dst = ((kt + 1) & 1) << 14;
#pragma unroll
      for (int i = 0; i < 4; i++) {
        gload_lds16(srcK[i] + (size_t)(kt + 1) * 8192,
                    lds + dst + i * 4096 + wid * 1024);
        gload_lds16(srcV[i] + (size_t)(kt + 1) * 64,
                    lds + 32768 + dst + i * 4096 + wid * 1024);
      }
      asm volatile("s_waitcnt vmcnt(8)" ::: "memory");  // drain stage(kt)
    } else {
      asm volatile("s_waitcnt vmcnt(0)" ::: "memory");
    }
    __builtin_amdgcn_s_barrier();

    const char* Kt = lds + (kt & 1) * 16384;
    const char* Vl = lds + 32768 + (kt & 1) * 16384;
    const int kbg = kt * 64;
    const bool active = (kbg <= q0w + 31);  // wave-uniform
    if (active) {
      u32 u[16];
      f32x16 s[2] = {};
      __builtin_amdgcn_s_setprio(1);
#pragma unroll
      for (int kg = 0; kg < 2; kg++) {
        const char* Kq = Kt + (kg * 32 + r32) * 256;
#pragma unroll
        for (int f = 0; f < 8; f++) {
          bf16x8 kf = *(const bf16x8*)(Kq + ((f * 32 + hh * 16) ^ xr));
          s[kg] = mfma32(kf, qf[f], s[kg]);
        }
      }
      __builtin_amdgcn_s_setprio(0);
      const bool maskt = (kbg + 63 > q0w);
      if (maskt) {
#pragma unroll
        for (int kg = 0; kg < 2; kg++)
#pragma unroll
          for (int r = 0; r < 16; r++)
            if (kbg + kg * 32 + (r & 3) + 8 * (r >> 2) + 4 * hh > qg)
              s[kg][r] = -1e30f;
      }
      // tree max over 32 values
      float mx[16];
#pragma unroll
      for (int r = 0; r < 16; r++) mx[r] = fmaxf(s[0][r], s[1][r]);
#pragma unroll
      for (int st = 8; st > 0; st >>= 1)
#pragma unroll
        for (int r = 0; r < 8; r++)
          if (r < st) mx[r] = fmaxf(mx[r], mx[r + st]);
      float tm = mx[0];
      tm = fmaxf(tm, __shfl_xor(tm, 32));
      // defer-max: rescale only when raw max grew by > 64 (5.7 nats scaled)
      if (!__all(tm <= m + 64.0f)) {
        float mnew = fmaxf(m, tm);
        float corr = __expf((m - mnew) * sc);
        m = mnew;
        l *= corr;
        if (lane < 32) *(float*)(Pc + r32 * 4) = corr;
        asm volatile("s_waitcnt lgkmcnt(0)" ::: "memory");
        __builtin_amdgcn_sched_barrier(0);
        f32x4 c0 = *(const f32x4*)(Pc + (4 * hh) * 4);
        f32x4 c1 = *(const f32x4*)(Pc + (8 + 4 * hh) * 4);
        f32x4 c2 = *(const f32x4*)(Pc + (16 + 4 * hh) * 4);
        f32x4 c3 = *(const f32x4*)(Pc + (24 + 4 * hh) * 4);
#pragma unroll
        for (int dg = 0; dg < 4; dg++)
#pragma unroll
          for (int r = 0; r < 16; r++) {
            float cr = (r >> 2) == 0 ? c0[r & 3]
                     : (r >> 2) == 1 ? c1[r & 3]
                     : (r >> 2) == 2 ? c2[r & 3] : c3[r & 3];
            acc[dg][r] *= cr;
          }
      }
      const float nms = -m * sc;
      float sm[16];
#pragma unroll
      for (int kg = 0; kg < 2; kg++)
#pragma unroll
        for (int r = 0; r < 16; r++)
          s[kg][r] = __expf(fmaf(s[kg][r], sc, nms));
      // tree sum over 32 values
#pragma unroll
      for (int r = 0; r < 16; r++) sm[r] = s[0][r] + s[1][r];
#pragma unroll
      for (int st = 8; st > 0; st >>= 1)
#pragma unroll
        for (int r = 0; r < 8; r++)
          if (r < st) sm[r] = sm[r] + sm[r + st];
      float ts = sm[0];
      ts += __shfl_xor(ts, 32);
      l += ts;
      // pack P pairs (keys kg*32 + 8*(i>>1) + 4*hh + 2*(i&1) + {0,1})
#pragma unroll
      for (int kg = 0; kg < 2; kg++)
#pragma unroll
        for (int i = 0; i < 8; i++)
          u[kg * 8 + i] = pack2(s[kg][2 * i], s[kg][2 * i + 1]);

      // PV: V(kt) ready (waited at top)
      __builtin_amdgcn_s_setprio(1);
#pragma unroll
      for (int dg = 0; dg < 4; dg++) {
        const char* Vq = Vl + (dg * 32 + r32) * 128;
#pragma unroll
        for (int ss = 0; ss < 4; ss++) {
          uint2 vlo = *(const uint2*)(Vq + ((ss * 32 + 8 * hh) ^ xr));
          uint2 vhi = *(const uint2*)(Vq + ((ss * 32 + 16 + 8 * hh) ^ xr));
          union { u32 w[4]; bf16x8 v; } vb, pa;
          vb.w[0] = vlo.x; vb.w[1] = vlo.y; vb.w[2] = vhi.x; vb.w[3] = vhi.y;
          pa.w[0] = u[ss * 4 + 0];
          pa.w[1] = u[ss * 4 + 1];
          pa.w[2] = u[ss * 4 + 2];
          pa.w[3] = u[ss * 4 + 3];
          acc[dg] = mfma32(pa.v, vb.v, acc[dg]);
        }
      }
      __builtin_amdgcn_s_setprio(0);
    }
    __builtin_amdgcn_s_barrier();  // reads of bufs(kt) done; safe to overwrite
  }

  float linv = 1.0f / l;
  if (lane < 32) *(float*)(Pc + r32 * 4) = linv;
  asm volatile("s_waitcnt lgkmcnt(0)" ::: "memory");
  __builtin_amdgcn_sched_barrier(0);
  f32x4 l0 = *(const f32x4*)(Pc + (4 * hh) * 4);
  f32x4 l1 = *(const f32x4*)(Pc + (8 + 4 * hh) * 4);
  f32x4 l2 = *(const f32x4*)(Pc + (16 + 4 * hh) * 4);
  f32x4 l3 = *(const f32x4*)(Pc + (24 + 4 * hh) * 4);
  u16* ab = attn + (size_t)(b * S + q0w) * 2048 + h * 128;
#pragma unroll
  for (int dg = 0; dg < 4; dg++)
#pragma unroll
    for (int r = 0; r < 16; r++) {
      int rowl = (r & 3) + 8 * (r >> 2) + 4 * hh;
      float li = (r >> 2) == 0 ? l0[r & 3]
               : (r >> 2) == 1 ? l1[r & 3]
               : (r >> 2) == 2 ? l2[r & 3] : l3[r & 3];
      ab[(size_t)rowl * 2048 + dg * 32 + r32] = f2bf(acc[dg][r] * li);
    }
}

// ---------------- launch ----------------
extern "C" void kernel_launch(void* const* d_in, const int* in_sizes, int n_in,
                              void* d_out, int out_size, void* d_ws, size_t ws_size,
                              hipStream_t stream) {
  (void)in_sizes; (void)n_in; (void)out_size; (void)ws_size;
  const int S = 2048;
  const float* x = (const float*)d_in[0];
  const float* qkv = (const float*)d_in[1];
  const float* wk = (const float*)d_in[2];
  const float* wo = (const float*)d_in[3];
  float* out = (float*)d_out;
  float* k_out = out + (size_t)8388608;
  float* v_out = out + (size_t)16777216;

  char* ws = (char*)d_ws;
  u16* x_bf  = (u16*)(ws + 0);          // 16.78 MB (later: attn_bf)
  u16* wcomb = (u16*)(ws + 16777216);   // 22.02 MB (5376x2048) (later: k_bf)
  u16* wo_bf = (u16*)(ws + 38797312);   // 8.39 MB
  u16* qvk   = (u16*)(ws + 47185920);   // 44.04 MB (4096x5376)
  u16* vt_bf = (u16*)(ws + 91226112);   // 16.78 MB (B,H,128,S)
  u16* attn_bf = x_bf;
  u16* k_bf = wcomb;

  cast_all<<<23040, 256, 0, stream>>>((const float4*)x, (const float4*)qkv, wk,
                                      (const float4*)wo, x_bf, wcomb, wo_bf);

  // Q+V: cols 0..4095 (one perfect round of 256 blocks)
  gemm256<u16, 256, 256><<<dim3(16, 16), 512, 0, stream>>>(x_bf, wcomb, qvk,
                                                           4096, 5376, 2048);
  // K-GEMM (160 blocks) + v_scatter (4096 blocks) in one dispatch
  kgemm_vscatter<<<4256, 512, 0, stream>>>(x_bf, wcomb + (size_t)4096 * 2048,
                                           qvk + 4096, qvk, vt_bf, v_out, S);
  rope_scatter2<<<4096, 256, 0, stream>>>(qvk, k_bf, k_out, S);
  flash_attn10<<<512, 256, 0, stream>>>(qvk, k_bf, vt_bf, attn_bf, S);
  gemm256<float, 128, 256><<<dim3(8, 32), 512, 0, stream>>>(attn_bf, wo_bf, out,
                                                            4096, 2048, 2048);
}